// Round 5
// baseline (372.924 us; speedup 1.0000x reference)
//
#include <hip/hip_runtime.h>
#include <hip/hip_cooperative_groups.h>
#include <math.h>

namespace cg = cooperative_groups;

#define DIM 1024
#define NQ 10
#define NL 4
#define SEQ 512
#define NROWS 4096
#define PRED 96

typedef unsigned short ushort_t;
typedef unsigned int uint_t;
using half8   = __attribute__((ext_vector_type(8))) _Float16;
using float4v = __attribute__((ext_vector_type(4))) float;

__device__ inline ushort_t f2h(float f) { _Float16 h = (_Float16)f; return *(ushort_t*)&h; }
__device__ inline uint_t pkh(float a, float b) {
    _Float16 ha = (_Float16)a, hb = (_Float16)b;   // RTE v_cvt_f16_f32
    return (uint_t)(*(ushort_t*)&ha) | ((uint_t)(*(ushort_t*)&hb) << 16);
}

// XOR-ladder layer permutation (GF(2)-linear). Verified R1-R4.
__device__ inline int permf(int s, int r) {
#pragma unroll
    for (int c = 9; c >= 0; --c) {
        int t = (c + r) % 10;
        s ^= ((s >> (9 - c)) & 1) << (9 - t);
    }
    return s;
}

#define GBM 128
#define GBNC 64
#define GBK 32
#define LDA 40   // half stride for LDS tiles
#define LDP 65   // float stride for probs tile

// ---------------------------------------------------------------------------
// One cooperative kernel, three phases separated by grid.sync():
//  1. circuit on 513 columns (wave-register, R4-verified math), one column
//     per block (wave 0) + bias column on block 0 wave 1; writes C s-major.
//  2. f16 MFMA GEMM + probs + signed partials (R3-verified body).
//  3. finalize: 8 rows/block, butterfly partial combine + W_out epilogue.
// ---------------------------------------------------------------------------
__global__ __launch_bounds__(256, 2)
void fused_kernel(const float* __restrict__ x, const float* __restrict__ Wi,
                  const float* __restrict__ b_in, const float* __restrict__ qw,
                  const float* __restrict__ W_out, const float* __restrict__ b_out,
                  ushort_t* __restrict__ Csm_r, ushort_t* __restrict__ Csm_i,
                  float* __restrict__ dr, float* __restrict__ di,
                  float* __restrict__ part, float* __restrict__ out)
{
    cg::grid_group grid = cg::this_grid();

    __shared__ __align__(16) char lds[GBM * LDP * 4];   // 33280 B, phase-shared
    __shared__ float gm[NL * NQ][8];
    __shared__ float drs[GBNC], dis[GBNC];
    __shared__ float evf8[8][12];

    const int tid = threadIdx.x;
    const int lane = tid & 63;
    const int wv = tid >> 6;
    const int blk = blockIdx.x;

    // ================= phase 1: circuit =================
    if (tid < NL * NQ) {
        float phi = qw[tid * 3 + 0], theta = qw[tid * 3 + 1], omega = qw[tid * 3 + 2];
        float ch = cosf(theta * 0.5f), sh = sinf(theta * 0.5f);
        float a = 0.5f * (phi + omega), b = 0.5f * (phi - omega);
        float ca = cosf(a), sa = sinf(a);
        float cb = cosf(b), sb = sinf(b);
        gm[tid][0] =  ch * ca;  gm[tid][1] = -ch * sa;   // m00
        gm[tid][2] = -sh * cb;  gm[tid][3] = -sh * sb;   // m01
        gm[tid][4] =  sh * cb;  gm[tid][5] = -sh * sb;   // m10
        gm[tid][6] =  ch * ca;  gm[tid][7] =  ch * sa;   // m11
    }
    __syncthreads();

    const int jcol = (wv == 0) ? blk : ((blk == 0 && wv == 1) ? SEQ : -1);
    if (jcol >= 0) {
        float2 P[16];
        if (jcol < SEQ) {
#pragma unroll
            for (int r = 0; r < 16; ++r)
                P[r] = make_float2(Wi[(size_t)(lane * 16 + r) * SEQ + jcol], 0.f);
        } else {
#pragma unroll
            for (int r = 0; r < 16; ++r)
                P[r] = make_float2(b_in[lane * 16 + r] + 1e-6f, 0.f);
        }
        float2* wscr = (float2*)lds + wv * 1024;   // wave-private 8 KB

#pragma unroll
        for (int l = 0; l < NL; ++l) {
#pragma unroll
            for (int w = 0; w < NQ; ++w) {
                const float* m = gm[l * NQ + w];
                float m00r = m[0], m00i = m[1], m01r = m[2], m01i = m[3];
                float m10r = m[4], m10i = m[5], m11r = m[6], m11i = m[7];
                if (w <= 5) {
                    const int lb = 5 - w;
                    const int mask = 1 << lb;
                    const int myb = (lane >> lb) & 1;
                    float cAr = myb ? m11r : m00r, cAi = myb ? m11i : m00i;
                    float cQr = myb ? m10r : m01r, cQi = myb ? m10i : m01i;
#pragma unroll
                    for (int r = 0; r < 16; ++r) {
                        float ar = P[r].x, ai = P[r].y;
                        float qr_ = __shfl_xor(ar, mask, 64);
                        float qi_ = __shfl_xor(ai, mask, 64);
                        P[r].x = cAr * ar - cAi * ai + cQr * qr_ - cQi * qi_;
                        P[r].y = cAr * ai + cAi * ar + cQr * qi_ + cQi * qr_;
                    }
                } else {
                    const int mk = 1 << (9 - w);
#pragma unroll
                    for (int r0 = 0; r0 < 16; ++r0) {
                        if (r0 & mk) continue;
                        float2 a0 = P[r0], a1 = P[r0 | mk];
                        float2 n0, n1;
                        n0.x = m00r * a0.x - m00i * a0.y + m01r * a1.x - m01i * a1.y;
                        n0.y = m00r * a0.y + m00i * a0.x + m01r * a1.y + m01i * a1.x;
                        n1.x = m10r * a0.x - m10i * a0.y + m11r * a1.x - m11i * a1.y;
                        n1.y = m10r * a0.y + m10i * a0.x + m11r * a1.y + m11i * a1.x;
                        P[r0] = n0; P[r0 | mk] = n1;
                    }
                }
            }
            const int rr = l % (NQ - 1) + 1;
#pragma unroll
            for (int r = 0; r < 16; ++r) wscr[lane * 16 + r] = P[r];
            int pl = permf(lane << 4, rr);
#pragma unroll
            for (int r = 0; r < 16; ++r) {
                int src = pl ^ permf(r, rr);
                P[r] = wscr[src];
            }
        }

        if (jcol < SEQ) {
#pragma unroll
            for (int r = 0; r < 16; ++r) {
                int s = lane * 16 + r;
                Csm_r[(size_t)s * SEQ + jcol] = f2h(P[r].x);
                Csm_i[(size_t)s * SEQ + jcol] = f2h(P[r].y);
            }
        } else {
#pragma unroll
            for (int r = 0; r < 16; ++r) {
                dr[lane * 16 + r] = P[r].x;
                di[lane * 16 + r] = P[r].y;
            }
        }
    }
    __threadfence();
    grid.sync();

    // ================= phase 2: GEMM + probs + partials =================
    {
        ushort_t* Ash = (ushort_t*)lds;
        ushort_t* Bsr = Ash + GBM * LDA;
        ushort_t* Bsi = Bsr + GBNC * LDA;
        float*    Ps  = (float*)lds;

        const int bm = blk & 31, bn = blk >> 5;
        const int n0 = bn * GBNC;

        if (tid < GBNC) { drs[tid] = dr[n0 + tid]; dis[tid] = di[n0 + tid]; }

        float4v accr[2][4], acci[2][4];
#pragma unroll
        for (int a = 0; a < 2; ++a)
#pragma unroll
            for (int b = 0; b < 4; ++b) { accr[a][b] = (float4v)0.f; acci[a][b] = (float4v)0.f; }

        const int sr = tid >> 1, ko = (tid & 1) * 16;
        const float* xa = x + (size_t)(bm * GBM + sr) * SEQ + ko;
        const int bsel = tid >> 7;
        const int nr = (tid & 127) >> 1;
        const int bko = (tid & 1) * 16;
        const ushort_t* bsrc = (bsel ? Csm_i : Csm_r) + (size_t)(n0 + nr) * SEQ + bko;
        ushort_t* bdst = (bsel ? Bsi : Bsr) + nr * LDA + bko;

        const int fm = lane & 15, kq = (lane >> 4) * 8;
        const int wrow = wv * 32;

        for (int k0 = 0; k0 < SEQ; k0 += GBK) {
            float fv[16];
            *(float4*)&fv[0]  = *(const float4*)(xa + k0);
            *(float4*)&fv[4]  = *(const float4*)(xa + k0 + 4);
            *(float4*)&fv[8]  = *(const float4*)(xa + k0 + 8);
            *(float4*)&fv[12] = *(const float4*)(xa + k0 + 12);
            uint_t pk[8];
#pragma unroll
            for (int i = 0; i < 8; ++i) pk[i] = pkh(fv[2 * i], fv[2 * i + 1]);
            uint4 b0 = *(const uint4*)(bsrc + k0);
            uint4 b1 = *(const uint4*)(bsrc + k0 + 8);
            __syncthreads();   // protect LDS from previous iteration's reads
            *(uint4*)(Ash + sr * LDA + ko)     = make_uint4(pk[0], pk[1], pk[2], pk[3]);
            *(uint4*)(Ash + sr * LDA + ko + 8) = make_uint4(pk[4], pk[5], pk[6], pk[7]);
            *(uint4*)bdst       = b0;
            *(uint4*)(bdst + 8) = b1;
            __syncthreads();

            half8 ah0 = *(half8*)(Ash + (wrow + fm) * LDA + kq);
            half8 ah1 = *(half8*)(Ash + (wrow + 16 + fm) * LDA + kq);
#pragma unroll
            for (int nt = 0; nt < 4; ++nt) {
                half8 br = *(half8*)(Bsr + (nt * 16 + fm) * LDA + kq);
                half8 bi = *(half8*)(Bsi + (nt * 16 + fm) * LDA + kq);
                accr[0][nt] = __builtin_amdgcn_mfma_f32_16x16x32_f16(ah0, br, accr[0][nt], 0, 0, 0);
                accr[1][nt] = __builtin_amdgcn_mfma_f32_16x16x32_f16(ah1, br, accr[1][nt], 0, 0, 0);
                acci[0][nt] = __builtin_amdgcn_mfma_f32_16x16x32_f16(ah0, bi, acci[0][nt], 0, 0, 0);
                acci[1][nt] = __builtin_amdgcn_mfma_f32_16x16x32_f16(ah1, bi, acci[1][nt], 0, 0, 0);
            }
        }
        __syncthreads();

        const int rq = (lane >> 4) * 4;
#pragma unroll
        for (int mt = 0; mt < 2; ++mt)
#pragma unroll
            for (int nt = 0; nt < 4; ++nt) {
                float drv = drs[nt * 16 + fm], div = dis[nt * 16 + fm];
#pragma unroll
                for (int reg = 0; reg < 4; ++reg) {
                    int lrow = wrow + mt * 16 + rq + reg;
                    float zr = accr[mt][nt][reg] + drv;
                    float zi = acci[mt][nt][reg] + div;
                    Ps[lrow * LDP + nt * 16 + fm] = zr * zr + zi * zi;
                }
            }
        __syncthreads();

        {
            const int row = tid >> 1, hh = tid & 1;
            const float* pr = Ps + row * LDP + hh * 32;
            float nrm = 0.f, e0 = 0.f, e1 = 0.f, e2 = 0.f, e3 = 0.f, e4 = 0.f, e5 = 0.f;
#pragma unroll
            for (int i = 0; i < 32; ++i) {
                float p = pr[i];
                int c = hh * 32 + i;
                nrm += p;
                e0 += ((c >> 5) & 1) ? -p : p;
                e1 += ((c >> 4) & 1) ? -p : p;
                e2 += ((c >> 3) & 1) ? -p : p;
                e3 += ((c >> 2) & 1) ? -p : p;
                e4 += ((c >> 1) & 1) ? -p : p;
                e5 += (c & 1) ? -p : p;
            }
            size_t base = ((size_t)(bm * GBM + row) * 32 + (bn * 2 + hh)) * 8;
            part[base + 0] = nrm;
            part[base + 1] = e0; part[base + 2] = e1; part[base + 3] = e2;
            part[base + 4] = e3; part[base + 5] = e4; part[base + 6] = e5;
        }
    }
    __threadfence();
    grid.sync();

    // ================= phase 3: finalize (8 rows per block) =================
    {
        const int rbase = blk * 8;
        const int half = lane >> 5, p = lane & 31;
        const int lrow = wv * 2 + half;
        const float* pp = part + ((size_t)(rbase + lrow) * 32 + p) * 8;
        float4 a = *(const float4*)pp;
        float4 b = *(const float4*)(pp + 4);
        float v[11];
        float nrm = a.x;
        int bnn = p >> 1;   // s bits 9..6 = bits 3..0 of bnn
        v[0] = nrm;
        v[1] = (bnn & 8) ? -nrm : nrm;
        v[2] = (bnn & 4) ? -nrm : nrm;
        v[3] = (bnn & 2) ? -nrm : nrm;
        v[4] = (bnn & 1) ? -nrm : nrm;
        v[5] = a.y; v[6] = a.z; v[7] = a.w;
        v[8] = b.x; v[9] = b.y; v[10] = b.z;
#pragma unroll
        for (int m = 16; m; m >>= 1)
#pragma unroll
            for (int k = 0; k < 11; ++k) v[k] += __shfl_xor(v[k], m, 64);
        if (p == 0) {
            float inv = 1.0f / v[0];
#pragma unroll
            for (int k = 0; k < 10; ++k) evf8[lrow][k] = v[k + 1] * inv;
        }
        __syncthreads();
        for (int t = tid; t < 8 * PRED; t += 256) {
            int rr = t / PRED, c = t - rr * PRED;
            float o = b_out[c];
#pragma unroll
            for (int k = 0; k < NQ; ++k) o = fmaf(W_out[c * NQ + k], evf8[rr][k], o);
            out[(size_t)(rbase + rr) * PRED + c] = o;
        }
    }
}

extern "C" void kernel_launch(void* const* d_in, const int* in_sizes, int n_in,
                              void* d_out, int out_size, void* d_ws, size_t ws_size,
                              hipStream_t stream) {
    const float* x     = (const float*)d_in[0];
    const float* W_in  = (const float*)d_in[1];
    const float* b_in  = (const float*)d_in[2];
    const float* qw    = (const float*)d_in[3];
    const float* W_out = (const float*)d_in[4];
    const float* b_out = (const float*)d_in[5];
    float* out = (float*)d_out;

    char* w = (char*)d_ws;
    const size_t MB = 1u << 20;
    ushort_t* Csm_r = (ushort_t*)w;               // 1 MB  [s][j]
    ushort_t* Csm_i = (ushort_t*)(w + 1 * MB);    // 1 MB
    float*    dr    = (float*)(w + 2 * MB);       // 4 KB
    float*    di    = dr + DIM;                   // 4 KB
    float*    part  = (float*)(w + 3 * MB);       // 4 MB

    void* args[] = {(void*)&x, (void*)&W_in, (void*)&b_in, (void*)&qw,
                    (void*)&W_out, (void*)&b_out,
                    (void*)&Csm_r, (void*)&Csm_i, (void*)&dr, (void*)&di,
                    (void*)&part, (void*)&out};
    hipLaunchCooperativeKernel((void*)fused_kernel, dim3(512), dim3(256),
                               args, 0, stream);
}

// Round 8
// 114.639 us; speedup vs baseline: 3.2530x; 3.2530x over previous
//
#include <hip/hip_runtime.h>
#include <math.h>

#define DIM 1024
#define NQ 10
#define NL 4
#define SEQ 512
#define NROWS 4096
#define PRED 96

typedef unsigned short ushort_t;
typedef unsigned int uint_t;
using half8   = __attribute__((ext_vector_type(8))) _Float16;
using float4v = __attribute__((ext_vector_type(4))) float;

__device__ inline ushort_t f2h(float f) { _Float16 h = (_Float16)f; return *(ushort_t*)&h; }
__device__ inline uint_t pkh(float a, float b) {
    _Float16 ha = (_Float16)a, hb = (_Float16)b;   // RTE v_cvt_f16_f32
    return (uint_t)(*(ushort_t*)&ha) | ((uint_t)(*(ushort_t*)&hb) << 16);
}

// ---------------------------------------------------------------------------
// Kernel 0: x (fp32) -> xh (f16), same layout. 8 floats/thread.
// (Verbatim from R4, which passed.)
// ---------------------------------------------------------------------------
__global__ __launch_bounds__(256)
void convert_x_kernel(const float* __restrict__ x, ushort_t* __restrict__ xh)
{
    int i = (blockIdx.x * 256 + threadIdx.x) * 8;
    float4 a = *(const float4*)(x + i);
    float4 b = *(const float4*)(x + i + 4);
    uint4 o;
    o.x = pkh(a.x, a.y); o.y = pkh(a.z, a.w);
    o.z = pkh(b.x, b.y); o.w = pkh(b.z, b.w);
    *(uint4*)(xh + i) = o;
}

// ---------------------------------------------------------------------------
// Kernel 1: circuit on 512 columns of W_in + bias column.
// (Verbatim from R3, which passed.)
// ---------------------------------------------------------------------------
__global__ __launch_bounds__(512)
void circuit_cols_kernel(const float* __restrict__ Wi, const float* __restrict__ b_in,
                         const float* __restrict__ qw,
                         ushort_t* __restrict__ Crt_r, ushort_t* __restrict__ Crt_i,
                         float* __restrict__ dr, float* __restrict__ di)
{
    __shared__ float2 psi[DIM];
    __shared__ float gm[NL * NQ][8];

    const int tid = threadIdx.x;
    const int j = blockIdx.x;

    if (tid < NL * NQ) {
        float phi = qw[tid * 3 + 0], theta = qw[tid * 3 + 1], omega = qw[tid * 3 + 2];
        float ch = cosf(theta * 0.5f), sh = sinf(theta * 0.5f);
        float a = 0.5f * (phi + omega), b = 0.5f * (phi - omega);
        float ca = cosf(a), sa = sinf(a);
        float cb = cosf(b), sb = sinf(b);
        gm[tid][0] =  ch * ca;  gm[tid][1] = -ch * sa;   // m00
        gm[tid][2] = -sh * cb;  gm[tid][3] = -sh * sb;   // m01
        gm[tid][4] =  sh * cb;  gm[tid][5] = -sh * sb;   // m10
        gm[tid][6] =  ch * ca;  gm[tid][7] =  ch * sa;   // m11
    }

    float v0, v1;
    if (j < SEQ) {
        v0 = Wi[(size_t)(2 * tid) * SEQ + j];
        v1 = Wi[(size_t)(2 * tid + 1) * SEQ + j];
    } else {
        v0 = b_in[2 * tid] + 1e-6f;
        v1 = b_in[2 * tid + 1] + 1e-6f;
    }
    psi[2 * tid]     = make_float2(v0, 0.f);
    psi[2 * tid + 1] = make_float2(v1, 0.f);
    __syncthreads();

    for (int l = 0; l < NL; ++l) {
#pragma unroll
        for (int w = 0; w < NQ; ++w) {
            const float* m = gm[l * NQ + w];
            float m00r = m[0], m00i = m[1], m01r = m[2], m01i = m[3];
            float m10r = m[4], m10i = m[5], m11r = m[6], m11i = m[7];
            int mask = 1 << (9 - w);
            int lo = tid & (mask - 1);
            int s0 = ((tid ^ lo) << 1) | lo;
            int s1 = s0 | mask;
            float2 a0 = psi[s0], a1 = psi[s1];
            float2 n0, n1;
            n0.x = m00r * a0.x - m00i * a0.y + m01r * a1.x - m01i * a1.y;
            n0.y = m00r * a0.y + m00i * a0.x + m01r * a1.y + m01i * a1.x;
            n1.x = m10r * a0.x - m10i * a0.y + m11r * a1.x - m11i * a1.y;
            n1.y = m10r * a0.y + m10i * a0.x + m11r * a1.y + m11i * a1.x;
            psi[s0] = n0; psi[s1] = n1;
            __syncthreads();
        }
        int r = l % (NQ - 1) + 1;
        int p0 = tid, p1 = tid + 512;
#pragma unroll
        for (int c = 9; c >= 0; --c) {
            int t = (c + r) % NQ;
            p0 ^= ((p0 >> (9 - c)) & 1) << (9 - t);
            p1 ^= ((p1 >> (9 - c)) & 1) << (9 - t);
        }
        float2 t0 = psi[p0], t1 = psi[p1];
        __syncthreads();
        psi[tid] = t0; psi[tid + 512] = t1;
        __syncthreads();
    }

    float2 o0 = psi[tid], o1 = psi[tid + 512];
    if (j < SEQ) {
        Crt_r[(size_t)tid * SEQ + j]         = f2h(o0.x);
        Crt_i[(size_t)tid * SEQ + j]         = f2h(o0.y);
        Crt_r[(size_t)(tid + 512) * SEQ + j] = f2h(o1.x);
        Crt_i[(size_t)(tid + 512) * SEQ + j] = f2h(o1.y);
    } else {
        dr[tid] = o0.x;        di[tid] = o0.y;
        dr[tid + 512] = o1.x;  di[tid + 512] = o1.y;
    }
}

// ---------------------------------------------------------------------------
// Kernel 2: fused f16-MFMA GEMM + probs + signed partials.
// R3's 128x64 body; the ONLY change is the A-staging source: pre-converted
// xh with in-loop uint4 pass-through loads — exactly as in R4's passing
// gemm (same load/store order, no prefetch hoisting, no guards).
// ---------------------------------------------------------------------------
#define GBM 128
#define GBNC 64
#define GBK 32
#define LDA 40   // half stride for LDS tiles
#define LDP 65   // float stride for probs tile

__global__ __launch_bounds__(256)
void gemm_fused_kernel(const ushort_t* __restrict__ xh,
                       const ushort_t* __restrict__ Crt_r, const ushort_t* __restrict__ Crt_i,
                       const float* __restrict__ dr, const float* __restrict__ di,
                       float* __restrict__ part)
{
    __shared__ __align__(16) char lds[GBM * LDP * 4];  // 33280 B (probs tile is max)
    ushort_t* Ash = (ushort_t*)lds;            // 128*40 halves = 10240 B
    ushort_t* Bsr = Ash + GBM * LDA;           // 64*40 = 5120 B
    ushort_t* Bsi = Bsr + GBNC * LDA;          // 64*40 = 5120 B
    float*    Ps  = (float*)lds;               // reused after K-loop
    __shared__ float drs[GBNC], dis[GBNC];

    const int tid = threadIdx.x;
    const int bm = blockIdx.x, bn = blockIdx.y;
    const int lane = tid & 63, wv = tid >> 6;
    const int n0 = bn * GBNC;

    if (tid < GBNC) { drs[tid] = dr[n0 + tid]; dis[tid] = di[n0 + tid]; }

    float4v accr[2][4], acci[2][4];
#pragma unroll
    for (int a = 0; a < 2; ++a)
#pragma unroll
        for (int b = 0; b < 4; ++b) { accr[a][b] = (float4v)0.f; acci[a][b] = (float4v)0.f; }

    // A staging: thread -> row sr (0..127), k offset ko (0 or 16); 16 halves
    const int sr = tid >> 1, ko = (tid & 1) * 16;
    const ushort_t* xa = xh + (size_t)(bm * GBM + sr) * SEQ + ko;
    // B staging: threads 0-127 real, 128-255 imag; 16 halves each
    const int bsel = tid >> 7;
    const int nr = (tid & 127) >> 1;
    const int bko = (tid & 1) * 16;
    const ushort_t* bsrc = (bsel ? Crt_i : Crt_r) + (size_t)(n0 + nr) * SEQ + bko;
    ushort_t* bdst = (bsel ? Bsi : Bsr) + nr * LDA + bko;

    const int fm = lane & 15, kq = (lane >> 4) * 8;
    const int wrow = wv * 32;

    for (int k0 = 0; k0 < SEQ; k0 += GBK) {
        uint4 a0 = *(const uint4*)(xa + k0);
        uint4 a1 = *(const uint4*)(xa + k0 + 8);
        *(uint4*)(Ash + sr * LDA + ko)     = a0;
        *(uint4*)(Ash + sr * LDA + ko + 8) = a1;
        uint4 b0 = *(const uint4*)(bsrc + k0);
        uint4 b1 = *(const uint4*)(bsrc + k0 + 8);
        *(uint4*)bdst       = b0;
        *(uint4*)(bdst + 8) = b1;
        __syncthreads();

        half8 ah0 = *(half8*)(Ash + (wrow + fm) * LDA + kq);
        half8 ah1 = *(half8*)(Ash + (wrow + 16 + fm) * LDA + kq);
#pragma unroll
        for (int nt = 0; nt < 4; ++nt) {
            half8 br = *(half8*)(Bsr + (nt * 16 + fm) * LDA + kq);
            half8 bi = *(half8*)(Bsi + (nt * 16 + fm) * LDA + kq);
            accr[0][nt] = __builtin_amdgcn_mfma_f32_16x16x32_f16(ah0, br, accr[0][nt], 0, 0, 0);
            accr[1][nt] = __builtin_amdgcn_mfma_f32_16x16x32_f16(ah1, br, accr[1][nt], 0, 0, 0);
            acci[0][nt] = __builtin_amdgcn_mfma_f32_16x16x32_f16(ah0, bi, acci[0][nt], 0, 0, 0);
            acci[1][nt] = __builtin_amdgcn_mfma_f32_16x16x32_f16(ah1, bi, acci[1][nt], 0, 0, 0);
        }
        __syncthreads();
    }

    // --- epilogue: p = zr^2 + zi^2 into LDS ---
    const int rq = (lane >> 4) * 4;
#pragma unroll
    for (int mt = 0; mt < 2; ++mt)
#pragma unroll
        for (int nt = 0; nt < 4; ++nt) {
            float drv = drs[nt * 16 + fm], div = dis[nt * 16 + fm];
#pragma unroll
            for (int reg = 0; reg < 4; ++reg) {
                int lrow = wrow + mt * 16 + rq + reg;
                float zr = accr[mt][nt][reg] + drv;
                float zi = acci[mt][nt][reg] + div;
                Ps[lrow * LDP + nt * 16 + fm] = zr * zr + zi * zi;
            }
        }
    __syncthreads();

    // --- signed partials over this block's 64 cols (low 6 bits of s) ---
    {
        const int row = tid >> 1, hh = tid & 1;
        const float* pr = Ps + row * LDP + hh * 32;
        float nrm = 0.f, e0 = 0.f, e1 = 0.f, e2 = 0.f, e3 = 0.f, e4 = 0.f, e5 = 0.f;
#pragma unroll
        for (int i = 0; i < 32; ++i) {
            float p = pr[i];
            int c = hh * 32 + i;
            nrm += p;
            e0 += ((c >> 5) & 1) ? -p : p;   // k=4
            e1 += ((c >> 4) & 1) ? -p : p;   // k=5
            e2 += ((c >> 3) & 1) ? -p : p;   // k=6
            e3 += ((c >> 2) & 1) ? -p : p;   // k=7
            e4 += ((c >> 1) & 1) ? -p : p;   // k=8
            e5 += (c & 1) ? -p : p;          // k=9
        }
        size_t base = ((size_t)(bm * GBM + row) * 32 + (bn * 2 + hh)) * 8;
        part[base + 0] = nrm;
        part[base + 1] = e0; part[base + 2] = e1; part[base + 3] = e2;
        part[base + 4] = e3; part[base + 5] = e4; part[base + 6] = e5;
    }
}

// ---------------------------------------------------------------------------
// Kernel 3: per-row wave-parallel combine of 32 partials + W_out epilogue.
// (Verbatim from R3, which passed.)
// ---------------------------------------------------------------------------
__global__ __launch_bounds__(128)
void finalize_kernel(const float* __restrict__ part, const float* __restrict__ W_out,
                     const float* __restrict__ b_out, float* __restrict__ out)
{
    __shared__ float evf[16];
    const int row = blockIdx.x, tid = threadIdx.x;

    if (tid < 64) {
        float v[11];
        if (tid < 32) {
            const float* p = part + ((size_t)row * 32 + tid) * 8;
            float4 a = *(const float4*)p;
            float4 b = *(const float4*)(p + 4);
            float nrm = a.x;
            int bnn = tid >> 1;   // s bits 9..6 = bits 3..0 of bnn
            v[0] = nrm;
            v[1] = (bnn & 8) ? -nrm : nrm;
            v[2] = (bnn & 4) ? -nrm : nrm;
            v[3] = (bnn & 2) ? -nrm : nrm;
            v[4] = (bnn & 1) ? -nrm : nrm;
            v[5] = a.y; v[6] = a.z; v[7] = a.w;
            v[8] = b.x; v[9] = b.y; v[10] = b.z;
        } else {
#pragma unroll
            for (int k = 0; k < 11; ++k) v[k] = 0.f;
        }
#pragma unroll
        for (int m = 16; m; m >>= 1)
#pragma unroll
            for (int k = 0; k < 11; ++k) v[k] += __shfl_xor(v[k], m, 64);
        if (tid == 0) {
            float inv = 1.0f / v[0];
#pragma unroll
            for (int k = 0; k < 10; ++k) evf[k] = v[k + 1] * inv;
        }
    }
    __syncthreads();
    if (tid < PRED) {
        float o = b_out[tid];
#pragma unroll
        for (int k = 0; k < NQ; ++k) o = fmaf(W_out[tid * NQ + k], evf[k], o);
        out[(size_t)row * PRED + tid] = o;
    }
}

extern "C" void kernel_launch(void* const* d_in, const int* in_sizes, int n_in,
                              void* d_out, int out_size, void* d_ws, size_t ws_size,
                              hipStream_t stream) {
    const float* x     = (const float*)d_in[0];
    const float* W_in  = (const float*)d_in[1];
    const float* b_in  = (const float*)d_in[2];
    const float* qw    = (const float*)d_in[3];
    const float* W_out = (const float*)d_in[4];
    const float* b_out = (const float*)d_in[5];
    float* out = (float*)d_out;

    char* w = (char*)d_ws;
    const size_t MB = 1u << 20;
    ushort_t* xh    = (ushort_t*)w;               // 4 MB  f16 x
    ushort_t* Crt_r = (ushort_t*)(w + 4 * MB);    // 1 MB  [s][j]
    ushort_t* Crt_i = (ushort_t*)(w + 5 * MB);    // 1 MB
    float*    dr    = (float*)(w + 6 * MB);       // 4 KB
    float*    di    = dr + DIM;                   // 4 KB
    float*    part  = (float*)(w + 7 * MB);       // 4 MB

    convert_x_kernel<<<NROWS * SEQ / (256 * 8), 256, 0, stream>>>(x, xh);
    circuit_cols_kernel<<<SEQ + 1, 512, 0, stream>>>(W_in, b_in, qw, Crt_r, Crt_i, dr, di);
    dim3 g2(NROWS / GBM, DIM / GBNC);
    gemm_fused_kernel<<<g2, 256, 0, stream>>>(xh, Crt_r, Crt_i, dr, di, part);
    finalize_kernel<<<NROWS, 128, 0, stream>>>(part, W_out, b_out, out);
}